// Round 1
// baseline (1331.877 us; speedup 1.0000x reference)
//
#include <hip/hip_runtime.h>

// Problem constants
#define BB     2
#define CC     256
#define HH     48
#define WW     48
#define NTOK   2304          // H*W
#define NHEADS 8
#define HDIM   32
#define NBH    16            // BB*NHEADS
#define SCALE_QK 0.17677669529663687f  // 1/sqrt(32)
#define KSEL1  1152          // N1 // 2
#define KSEL2  768           // N1 // 3

__device__ __forceinline__ unsigned f2ord(float f) {
  unsigned u = __float_as_uint(f);
  return (u & 0x80000000u) ? ~u : (u | 0x80000000u);
}
__device__ __forceinline__ float ord2f(unsigned u) {
  unsigned b = (u & 0x80000000u) ? (u & 0x7fffffffu) : ~u;
  return __uint_as_float(b);
}

// ---------------------------------------------------------------------------
// Kernel A: multi-scale avg pool (3,5,7 box filters, count_include_pad) via
// per-plane integral image. One block per (b,c) plane.
__global__ __launch_bounds__(256) void pool_kernel(const float* __restrict__ y,
                                                   float* __restrict__ yp) {
  __shared__ float sp[HH * WW];
  __shared__ float I[49 * 49];
  const int bc = blockIdx.x;
  const float* src = y + (size_t)bc * (HH * WW);
  for (int i = threadIdx.x; i < HH * WW; i += 256) sp[i] = src[i];
  __syncthreads();
  if (threadIdx.x < 48) {            // row prefix sums
    int r = threadIdx.x;
    float acc = 0.f;
    I[(r + 1) * 49 + 0] = 0.f;
    for (int j = 0; j < 48; ++j) { acc += sp[r * 48 + j]; I[(r + 1) * 49 + j + 1] = acc; }
  } else if (threadIdx.x < 97) {     // zero top row
    int j = threadIdx.x - 48;
    I[j] = 0.f;
  }
  __syncthreads();
  if (threadIdx.x < 48) {            // column prefix sums
    int j = threadIdx.x + 1;
    float acc = 0.f;
    for (int i = 1; i <= 48; ++i) { acc += I[i * 49 + j]; I[i * 49 + j] = acc; }
  }
  __syncthreads();
  for (int n = threadIdx.x; n < HH * WW; n += 256) {
    int i = n / 48, j = n % 48;
    float r = 0.f;
#pragma unroll
    for (int kk = 0; kk < 3; ++kk) {
      int p = 1 + kk;                 // kernel 3,5,7 -> pad 1,2,3
      int i0 = i - p; if (i0 < 0) i0 = 0;
      int j0 = j - p; if (j0 < 0) j0 = 0;
      int i1 = i + p + 1; if (i1 > 48) i1 = 48;
      int j1 = j + p + 1; if (j1 > 48) j1 = 48;
      float s = I[i1 * 49 + j1] - I[i0 * 49 + j1] - I[i1 * 49 + j0] + I[i0 * 49 + j0];
      int k = 2 * p + 1;
      r += s / (float)(k * k);
    }
    yp[(size_t)bc * (HH * WW) + n] = r;
  }
}

// ---------------------------------------------------------------------------
// Kernel B: LayerNorm over C, transpose to [B, N, C]. One block per (b,n).
__global__ __launch_bounds__(256) void ln_kernel(const float* __restrict__ yp,
                                                 const float* __restrict__ gamma,
                                                 const float* __restrict__ beta,
                                                 float* __restrict__ yt) {
  const int bn = blockIdx.x;
  const int b = bn / NTOK, n = bn % NTOK;
  const int c = threadIdx.x;
  float v = yp[((size_t)(b * CC + c)) * NTOK + n];
  float s = v, s2 = v * v;
#pragma unroll
  for (int off = 32; off; off >>= 1) { s += __shfl_down(s, off); s2 += __shfl_down(s2, off); }
  __shared__ float ws[8];
  int wid = threadIdx.x >> 6, lane = threadIdx.x & 63;
  if (lane == 0) { ws[wid] = s; ws[4 + wid] = s2; }
  __syncthreads();
  s = ws[0] + ws[1] + ws[2] + ws[3];
  s2 = ws[4] + ws[5] + ws[6] + ws[7];
  float mean = s * (1.f / CC);
  float var = s2 * (1.f / CC) - mean * mean;
  float rstd = rsqrtf(var + 1e-5f);
  yt[(size_t)bn * CC + c] = (v - mean) * rstd * gamma[c] + beta[c];
}

// ---------------------------------------------------------------------------
// Generic 64x64-tile fp32 GEMM: C = A[M,K] @ B[K,Nc] (+bias).
// ATRANS=1: A is x in [B,C,N] layout, A[row,k] = x[b,k,n].
// trans_out=1: write Cm[b, col, n] (for the final projection into d_out).
template <int ATRANS>
__global__ __launch_bounds__(256) void gemm64_kernel(const float* __restrict__ A,
                                                     const float* __restrict__ Bm,
                                                     const float* __restrict__ bias,
                                                     float* __restrict__ Cm,
                                                     int K, int Nc, int trans_out) {
  __shared__ float smem[64 * 65];      // reused: As[16][68] + Bs[16][68], then Ts[64][65]
  float* As = smem;
  float* Bs = smem + 16 * 68;
  const int row0 = blockIdx.x * 64;
  const int col0 = blockIdx.y * 64;
  const int tid = threadIdx.x;
  const int ty = tid >> 4, tx = tid & 15;
  const int b = row0 / NTOK, n0 = row0 % NTOK;
  float acc[4][4] = {};
  for (int k0 = 0; k0 < K; k0 += 16) {
    if (ATRANS) {
#pragma unroll
      for (int it = 0; it < 4; ++it) {
        int idx = tid + it * 256;
        int kk = idx >> 6, r = idx & 63;
        As[kk * 68 + r] = A[((size_t)(b * CC + k0 + kk)) * NTOK + n0 + r];
      }
    } else {
#pragma unroll
      for (int it = 0; it < 4; ++it) {
        int idx = tid + it * 256;
        int kk = idx & 15, r = idx >> 4;
        As[kk * 68 + r] = A[(size_t)(row0 + r) * K + k0 + kk];
      }
    }
#pragma unroll
    for (int it = 0; it < 4; ++it) {
      int idx = tid + it * 256;
      int kk = idx >> 6, c = idx & 63;
      Bs[kk * 68 + c] = Bm[(size_t)(k0 + kk) * Nc + col0 + c];
    }
    __syncthreads();
#pragma unroll
    for (int kk = 0; kk < 16; ++kk) {
      float a0[4], b0[4];
#pragma unroll
      for (int i = 0; i < 4; ++i) a0[i] = As[kk * 68 + ty * 4 + i];
#pragma unroll
      for (int j = 0; j < 4; ++j) b0[j] = Bs[kk * 68 + tx * 4 + j];
#pragma unroll
      for (int i = 0; i < 4; ++i)
#pragma unroll
        for (int j = 0; j < 4; ++j) acc[i][j] += a0[i] * b0[j];
    }
    __syncthreads();
  }
  if (!trans_out) {
#pragma unroll
    for (int i = 0; i < 4; ++i)
#pragma unroll
      for (int j = 0; j < 4; ++j) {
        int row = row0 + ty * 4 + i, col = col0 + tx * 4 + j;
        float v = acc[i][j] + (bias ? bias[col] : 0.f);
        Cm[(size_t)row * Nc + col] = v;
      }
  } else {
    float* Ts = smem;
#pragma unroll
    for (int i = 0; i < 4; ++i)
#pragma unroll
      for (int j = 0; j < 4; ++j) Ts[(ty * 4 + i) * 65 + tx * 4 + j] = acc[i][j];
    __syncthreads();
#pragma unroll
    for (int it = 0; it < 16; ++it) {
      int idx = tid + it * 256;
      int c = idx >> 6, r = idx & 63;
      float v = Ts[r * 65 + c] + (bias ? bias[col0 + c] : 0.f);
      Cm[((size_t)(b * Nc + col0 + c)) * NTOK + n0 + r] = v;
    }
  }
}

// ---------------------------------------------------------------------------
// Kernel D: scores = scale * q @ k^T, per (b,h) slice. Chunked over bh.
__global__ __launch_bounds__(256) void score_kernel(const float* __restrict__ qm,
                                                    const float* __restrict__ kvm,
                                                    float* __restrict__ sc, int bh0) {
  __shared__ float Qs[32 * 68];
  __shared__ float Ks[32 * 68];
  const int n0 = blockIdx.x * 64, m0 = blockIdx.y * 64;
  const int z = blockIdx.z;
  const int gbh = bh0 + z;
  const int b = gbh >> 3, h = gbh & 7;
  const int tid = threadIdx.x;
  {
    int kk = tid & 31, rb = tid >> 5;
#pragma unroll
    for (int i = 0; i < 8; ++i) {
      int r = rb * 8 + i;
      Qs[kk * 68 + r] = qm[((size_t)(b * NTOK + n0 + r)) * CC + h * HDIM + kk];
      Ks[kk * 68 + r] = kvm[((size_t)(b * NTOK + m0 + r)) * (2 * CC) + h * HDIM + kk];
    }
  }
  __syncthreads();
  const int ty = tid >> 4, tx = tid & 15;
  float acc[4][4] = {};
#pragma unroll
  for (int kk = 0; kk < 32; ++kk) {
    float a0[4], b0[4];
#pragma unroll
    for (int i = 0; i < 4; ++i) a0[i] = Qs[kk * 68 + ty * 4 + i];
#pragma unroll
    for (int j = 0; j < 4; ++j) b0[j] = Ks[kk * 68 + tx * 4 + j];
#pragma unroll
    for (int i = 0; i < 4; ++i)
#pragma unroll
      for (int j = 0; j < 4; ++j) acc[i][j] += a0[i] * b0[j];
  }
#pragma unroll
  for (int i = 0; i < 4; ++i) {
    size_t rowbase = ((size_t)z * NTOK + n0 + ty * 4 + i) * NTOK + m0;
#pragma unroll
    for (int j = 0; j < 4; ++j) sc[rowbase + tx * 4 + j] = acc[i][j] * SCALE_QK;
  }
}

// ---------------------------------------------------------------------------
// Kernel E: per-row max, radix-select thresholds for k=1152 and k=768,
// partial exp-sums D1, D2. One block (256 threads) per score row.
__global__ __launch_bounds__(256) void select_kernel(const float* __restrict__ sc,
                                                     float* __restrict__ stats,
                                                     const float* __restrict__ w1p,
                                                     const float* __restrict__ w2p) {
  __shared__ float srow[NTOK];
  __shared__ unsigned hist[256];
  __shared__ unsigned sufx[256];
  __shared__ float red[8];
  __shared__ unsigned sres[2];
  const int tid = threadIdx.x;
  const size_t base = (size_t)blockIdx.x * NTOK;
  float mx = -3.4e38f;
  for (int j = tid; j < NTOK; j += 256) {
    float v = sc[base + j];
    srow[j] = v;
    mx = fmaxf(mx, v);
  }
#pragma unroll
  for (int off = 32; off; off >>= 1) mx = fmaxf(mx, __shfl_down(mx, off));
  if ((tid & 63) == 0) red[tid >> 6] = mx;
  __syncthreads();
  mx = fmaxf(fmaxf(red[0], red[1]), fmaxf(red[2], red[3]));

  unsigned thr[2];
  const int kwant[2] = {KSEL1, KSEL2};
  for (int sel = 0; sel < 2; ++sel) {
    unsigned prefix = 0, pmask = 0;
    unsigned krem = (unsigned)kwant[sel];
    for (int lvl = 3; lvl >= 0; --lvl) {
      const int shift = lvl * 8;
      hist[tid] = 0;
      __syncthreads();
      for (int j = tid; j < NTOK; j += 256) {
        unsigned u = f2ord(srow[j]);
        if ((u & pmask) == prefix) atomicAdd(&hist[(u >> shift) & 255u], 1u);
      }
      __syncthreads();
      sufx[tid] = hist[tid];
      __syncthreads();
      for (int off = 1; off < 256; off <<= 1) {   // suffix (reverse) scan
        unsigned t = (tid + off < 256) ? sufx[tid + off] : 0u;
        __syncthreads();
        sufx[tid] += t;
        __syncthreads();
      }
      unsigned mine = sufx[tid];
      unsigned above = (tid < 255) ? sufx[tid + 1] : 0u;
      if (mine >= krem && above < krem) { sres[0] = (unsigned)tid; sres[1] = krem - above; }
      __syncthreads();
      prefix |= sres[0] << shift;
      pmask |= 0xFFu << shift;
      krem = sres[1];
      __syncthreads();
    }
    thr[sel] = prefix;
  }
  const float t1 = ord2f(thr[0]), t2 = ord2f(thr[1]);
  float d1 = 0.f, d2 = 0.f;
  for (int j = tid; j < NTOK; j += 256) {
    float v = srow[j];
    float e = __expf(v - mx);
    if (v >= t1) d1 += e;
    if (v >= t2) d2 += e;
  }
#pragma unroll
  for (int off = 32; off; off >>= 1) { d1 += __shfl_down(d1, off); d2 += __shfl_down(d2, off); }
  if ((tid & 63) == 0) { red[tid >> 6] = d1; red[4 + (tid >> 6)] = d2; }
  __syncthreads();
  if (tid == 0) {
    d1 = red[0] + red[1] + red[2] + red[3];
    d2 = red[4] + red[5] + red[6] + red[7];
    float* st = stats + (size_t)blockIdx.x * 8;
    st[0] = mx;
    st[1] = t1;
    st[2] = t2;
    st[3] = w1p[0] / d1;
    st[4] = w2p[0] / d2;
  }
}

// ---------------------------------------------------------------------------
// Kernel F: out[b,n,h*32+d] = sum_m weight(s[n,m]) * v[m,d], 32-row tiles.
__global__ __launch_bounds__(256) void pv_kernel(const float* __restrict__ sc,
                                                 const float* __restrict__ kvm,
                                                 const float* __restrict__ stats,
                                                 float* __restrict__ oat, int bh0) {
  __shared__ float Vs[64 * 33];
  __shared__ float Wt[64 * 33];
  __shared__ float rst[32][5];
  const int rt = blockIdx.x;          // 0..71 (32-row tiles)
  const int z = blockIdx.y;           // local bh
  const int gbh = bh0 + z;
  const int b = gbh >> 3, h = gbh & 7;
  const int n0 = rt * 32;
  const int tid = threadIdx.x;
  if (tid < 160) {
    int r = tid / 5, f = tid % 5;
    rst[r][f] = stats[((size_t)z * NTOK + n0 + r) * 8 + f];
  }
  __syncthreads();
  const int g = tid >> 5, d = tid & 31;
  float acc[4] = {0.f, 0.f, 0.f, 0.f};
  for (int m0 = 0; m0 < NTOK; m0 += 64) {
#pragma unroll
    for (int i = 0; i < 8; ++i) {       // stage V tile [64 m][32 d]
      int idx = tid + i * 256;
      int mm = idx >> 5, dd = idx & 31;
      Vs[mm * 33 + dd] = kvm[((size_t)(b * NTOK + m0 + mm)) * (2 * CC) + CC + h * HDIM + dd];
    }
#pragma unroll
    for (int i = 0; i < 8; ++i) {       // stage weights Wt[mm][r]
      int idx = tid + i * 256;
      int r = idx >> 6, mm = idx & 63;
      float s = sc[((size_t)z * NTOK + n0 + r) * NTOK + m0 + mm];
      float e = __expf(s - rst[r][0]);
      float w = 0.f;
      if (s >= rst[r][1]) w += rst[r][3];
      if (s >= rst[r][2]) w += rst[r][4];
      Wt[mm * 33 + r] = e * w;
    }
    __syncthreads();
#pragma unroll 4
    for (int mm = 0; mm < 64; ++mm) {
      float vv = Vs[mm * 33 + d];
#pragma unroll
      for (int i = 0; i < 4; ++i) acc[i] += Wt[mm * 33 + g * 4 + i] * vv;
    }
    __syncthreads();
  }
#pragma unroll
  for (int i = 0; i < 4; ++i) {
    int n = n0 + g * 4 + i;
    oat[((size_t)(b * NTOK + n)) * CC + h * HDIM + d] = acc[i];
  }
}

// ---------------------------------------------------------------------------
extern "C" void kernel_launch(void* const* d_in, const int* in_sizes, int n_in,
                              void* d_out, int out_size, void* d_ws, size_t ws_size,
                              hipStream_t stream) {
  const float* x     = (const float*)d_in[0];
  const float* y     = (const float*)d_in[1];
  const float* Wq    = (const float*)d_in[2];
  const float* Wkv   = (const float*)d_in[3];
  const float* Wproj = (const float*)d_in[4];
  const float* bproj = (const float*)d_in[5];
  const float* gamma = (const float*)d_in[6];
  const float* beta  = (const float*)d_in[7];
  const float* aw1   = (const float*)d_in[8];
  const float* aw2   = (const float*)d_in[9];

  float* ws = (float*)d_ws;
  const size_t SZ_PLANE = (size_t)BB * CC * NTOK;          // 1,179,648
  float* yp    = ws;                                       // [B,C,N]
  float* yt    = yp + SZ_PLANE;                            // [B,N,C]
  float* qb    = yt + SZ_PLANE;                            // [B,N,C]
  float* kvb   = qb + SZ_PLANE;                            // [B,N,2C]
  float* stats = kvb + 2 * SZ_PLANE;                       // [16*2304, 8]
  float* oat   = stats + (size_t)NBH * NTOK * 8;           // [B,N,C]
  float* sc    = oat + SZ_PLANE;                           // [CH, N, N]

  // choose bh-chunk size from available workspace
  const long long fixed_f = (long long)(sc - ws);
  const long long avail_f = (long long)(ws_size / 4) - fixed_f;
  int CH = 16;
  while (CH > 1 && (long long)CH * NTOK * NTOK > avail_f) CH >>= 1;

  pool_kernel<<<dim3(BB * CC), 256, 0, stream>>>(y, yp);
  ln_kernel<<<dim3(BB * NTOK), 256, 0, stream>>>(yp, gamma, beta, yt);
  gemm64_kernel<1><<<dim3(BB * NTOK / 64, CC / 64), 256, 0, stream>>>(
      x, Wq, nullptr, qb, CC, CC, 0);
  gemm64_kernel<0><<<dim3(BB * NTOK / 64, 2 * CC / 64), 256, 0, stream>>>(
      yt, Wkv, nullptr, kvb, CC, 2 * CC, 0);

  const int nch = NBH / CH;
  for (int ch = 0; ch < nch; ++ch) {
    int bh0 = ch * CH;
    score_kernel<<<dim3(NTOK / 64, NTOK / 64, CH), 256, 0, stream>>>(qb, kvb, sc, bh0);
    select_kernel<<<dim3(CH * NTOK), 256, 0, stream>>>(sc, stats, aw1, aw2);
    pv_kernel<<<dim3(NTOK / 32, CH), 256, 0, stream>>>(sc, kvb, stats, oat, bh0);
  }

  gemm64_kernel<0><<<dim3(BB * NTOK / 64, CC / 64), 256, 0, stream>>>(
      oat, Wproj, bproj, (float*)d_out, CC, CC, 1);
}

// Round 2
// 1302.011 us; speedup vs baseline: 1.0229x; 1.0229x over previous
//
#include <hip/hip_runtime.h>

// Problem constants
#define BB     2
#define CC     256
#define HH     48
#define WW     48
#define NTOK   2304          // H*W
#define NHEADS 8
#define HDIM   32
#define NBH    16            // BB*NHEADS
#define SCALE_QK 0.17677669529663687f  // 1/sqrt(32)
#define KSEL1  1152          // N1 // 2
#define KSEL2  768           // N1 // 3

__device__ __forceinline__ unsigned f2ord(float f) {
  unsigned u = __float_as_uint(f);
  return (u & 0x80000000u) ? ~u : (u | 0x80000000u);
}
__device__ __forceinline__ float ord2f(unsigned u) {
  unsigned b = (u & 0x80000000u) ? (u & 0x7fffffffu) : ~u;
  return __uint_as_float(b);
}

// ---------------------------------------------------------------------------
// Kernel A: multi-scale avg pool (3,5,7 box filters, count_include_pad) via
// per-plane integral image. One block per (b,c) plane.
__global__ __launch_bounds__(256) void pool_kernel(const float* __restrict__ y,
                                                   float* __restrict__ yp) {
  __shared__ float sp[HH * WW];
  __shared__ float I[49 * 49];
  const int bc = blockIdx.x;
  const float* src = y + (size_t)bc * (HH * WW);
  for (int i = threadIdx.x; i < HH * WW; i += 256) sp[i] = src[i];
  __syncthreads();
  if (threadIdx.x < 48) {            // row prefix sums
    int r = threadIdx.x;
    float acc = 0.f;
    I[(r + 1) * 49 + 0] = 0.f;
    for (int j = 0; j < 48; ++j) { acc += sp[r * 48 + j]; I[(r + 1) * 49 + j + 1] = acc; }
  } else if (threadIdx.x < 97) {     // zero top row
    int j = threadIdx.x - 48;
    I[j] = 0.f;
  }
  __syncthreads();
  if (threadIdx.x < 48) {            // column prefix sums
    int j = threadIdx.x + 1;
    float acc = 0.f;
    for (int i = 1; i <= 48; ++i) { acc += I[i * 49 + j]; I[i * 49 + j] = acc; }
  }
  __syncthreads();
  for (int n = threadIdx.x; n < HH * WW; n += 256) {
    int i = n / 48, j = n % 48;
    float r = 0.f;
#pragma unroll
    for (int kk = 0; kk < 3; ++kk) {
      int p = 1 + kk;                 // kernel 3,5,7 -> pad 1,2,3
      int i0 = i - p; if (i0 < 0) i0 = 0;
      int j0 = j - p; if (j0 < 0) j0 = 0;
      int i1 = i + p + 1; if (i1 > 48) i1 = 48;
      int j1 = j + p + 1; if (j1 > 48) j1 = 48;
      float s = I[i1 * 49 + j1] - I[i0 * 49 + j1] - I[i1 * 49 + j0] + I[i0 * 49 + j0];
      int k = 2 * p + 1;
      r += s / (float)(k * k);
    }
    yp[(size_t)bc * (HH * WW) + n] = r;
  }
}

// ---------------------------------------------------------------------------
// Kernel B: LayerNorm over C, transpose to [B, N, C]. One block per (b,n).
__global__ __launch_bounds__(256) void ln_kernel(const float* __restrict__ yp,
                                                 const float* __restrict__ gamma,
                                                 const float* __restrict__ beta,
                                                 float* __restrict__ yt) {
  const int bn = blockIdx.x;
  const int b = bn / NTOK, n = bn % NTOK;
  const int c = threadIdx.x;
  float v = yp[((size_t)(b * CC + c)) * NTOK + n];
  float s = v, s2 = v * v;
#pragma unroll
  for (int off = 32; off; off >>= 1) { s += __shfl_down(s, off); s2 += __shfl_down(s2, off); }
  __shared__ float ws[8];
  int wid = threadIdx.x >> 6, lane = threadIdx.x & 63;
  if (lane == 0) { ws[wid] = s; ws[4 + wid] = s2; }
  __syncthreads();
  s = ws[0] + ws[1] + ws[2] + ws[3];
  s2 = ws[4] + ws[5] + ws[6] + ws[7];
  float mean = s * (1.f / CC);
  float var = s2 * (1.f / CC) - mean * mean;
  float rstd = rsqrtf(var + 1e-5f);
  yt[(size_t)bn * CC + c] = (v - mean) * rstd * gamma[c] + beta[c];
}

// ---------------------------------------------------------------------------
// Generic 64x64-tile fp32 GEMM: C = A[M,K] @ B[K,Nc] (+bias).
// ATRANS=1: A is x in [B,C,N] layout, A[row,k] = x[b,k,n].
// trans_out=1: write Cm[b, col, n] (for the final projection into d_out).
template <int ATRANS>
__global__ __launch_bounds__(256) void gemm64_kernel(const float* __restrict__ A,
                                                     const float* __restrict__ Bm,
                                                     const float* __restrict__ bias,
                                                     float* __restrict__ Cm,
                                                     int K, int Nc, int trans_out) {
  __shared__ float smem[64 * 65];      // reused: As[16][68] + Bs[16][68], then Ts[64][65]
  float* As = smem;
  float* Bs = smem + 16 * 68;
  const int row0 = blockIdx.x * 64;
  const int col0 = blockIdx.y * 64;
  const int tid = threadIdx.x;
  const int ty = tid >> 4, tx = tid & 15;
  const int b = row0 / NTOK, n0 = row0 % NTOK;
  float acc[4][4] = {};
  for (int k0 = 0; k0 < K; k0 += 16) {
    if (ATRANS) {
#pragma unroll
      for (int it = 0; it < 4; ++it) {
        int idx = tid + it * 256;
        int kk = idx >> 6, r = idx & 63;
        As[kk * 68 + r] = A[((size_t)(b * CC + k0 + kk)) * NTOK + n0 + r];
      }
    } else {
#pragma unroll
      for (int it = 0; it < 4; ++it) {
        int idx = tid + it * 256;
        int kk = idx & 15, r = idx >> 4;
        As[kk * 68 + r] = A[(size_t)(row0 + r) * K + k0 + kk];
      }
    }
#pragma unroll
    for (int it = 0; it < 4; ++it) {
      int idx = tid + it * 256;
      int kk = idx >> 6, c = idx & 63;
      Bs[kk * 68 + c] = Bm[(size_t)(k0 + kk) * Nc + col0 + c];
    }
    __syncthreads();
#pragma unroll
    for (int kk = 0; kk < 16; ++kk) {
      float a0[4], b0[4];
#pragma unroll
      for (int i = 0; i < 4; ++i) a0[i] = As[kk * 68 + ty * 4 + i];
#pragma unroll
      for (int j = 0; j < 4; ++j) b0[j] = Bs[kk * 68 + tx * 4 + j];
#pragma unroll
      for (int i = 0; i < 4; ++i)
#pragma unroll
        for (int j = 0; j < 4; ++j) acc[i][j] += a0[i] * b0[j];
    }
    __syncthreads();
  }
  if (!trans_out) {
#pragma unroll
    for (int i = 0; i < 4; ++i)
#pragma unroll
      for (int j = 0; j < 4; ++j) {
        int row = row0 + ty * 4 + i, col = col0 + tx * 4 + j;
        float v = acc[i][j] + (bias ? bias[col] : 0.f);
        Cm[(size_t)row * Nc + col] = v;
      }
  } else {
    float* Ts = smem;
    __syncthreads();
#pragma unroll
    for (int i = 0; i < 4; ++i)
#pragma unroll
      for (int j = 0; j < 4; ++j) Ts[(ty * 4 + i) * 65 + tx * 4 + j] = acc[i][j];
    __syncthreads();
#pragma unroll
    for (int it = 0; it < 16; ++it) {
      int idx = tid + it * 256;
      int c = idx >> 6, r = idx & 63;
      float v = Ts[r * 65 + c] + (bias ? bias[col0 + c] : 0.f);
      Cm[((size_t)(b * Nc + col0 + c)) * NTOK + n0 + r] = v;
    }
  }
}

// ---------------------------------------------------------------------------
// Kernel D: scores = scale * q @ k^T, per (b,h) slice. Chunked over bh.
__global__ __launch_bounds__(256) void score_kernel(const float* __restrict__ qm,
                                                    const float* __restrict__ kvm,
                                                    float* __restrict__ sc, int bh0) {
  __shared__ float Qs[32 * 68];
  __shared__ float Ks[32 * 68];
  const int n0 = blockIdx.x * 64, m0 = blockIdx.y * 64;
  const int z = blockIdx.z;
  const int gbh = bh0 + z;
  const int b = gbh >> 3, h = gbh & 7;
  const int tid = threadIdx.x;
  {
    int kk = tid & 31, rb = tid >> 5;
#pragma unroll
    for (int i = 0; i < 8; ++i) {
      int r = rb * 8 + i;
      Qs[kk * 68 + r] = qm[((size_t)(b * NTOK + n0 + r)) * CC + h * HDIM + kk];
      Ks[kk * 68 + r] = kvm[((size_t)(b * NTOK + m0 + r)) * (2 * CC) + h * HDIM + kk];
    }
  }
  __syncthreads();
  const int ty = tid >> 4, tx = tid & 15;
  float acc[4][4] = {};
#pragma unroll
  for (int kk = 0; kk < 32; ++kk) {
    float a0[4], b0[4];
#pragma unroll
    for (int i = 0; i < 4; ++i) a0[i] = Qs[kk * 68 + ty * 4 + i];
#pragma unroll
    for (int j = 0; j < 4; ++j) b0[j] = Ks[kk * 68 + tx * 4 + j];
#pragma unroll
    for (int i = 0; i < 4; ++i)
#pragma unroll
      for (int j = 0; j < 4; ++j) acc[i][j] += a0[i] * b0[j];
  }
#pragma unroll
  for (int i = 0; i < 4; ++i) {
    size_t rowbase = ((size_t)z * NTOK + n0 + ty * 4 + i) * NTOK + m0;
#pragma unroll
    for (int j = 0; j < 4; ++j) sc[rowbase + tx * 4 + j] = acc[i][j] * SCALE_QK;
  }
}

// ---------------------------------------------------------------------------
// Kernel E: per-row max, radix-select thresholds for k=1152 and k=768,
// partial exp-sums D1, D2. One block (256 threads) per score row.
// Level-3 (top byte) histogram fused into load pass and shared by both sels;
// per-wave sub-histograms cut LDS atomic contention; suffix scan done by
// wave 0 via shuffles (no barrier ladder).
__global__ __launch_bounds__(256) void select_kernel(const float* __restrict__ sc,
                                                     float* __restrict__ stats,
                                                     const float* __restrict__ w1p,
                                                     const float* __restrict__ w2p) {
  __shared__ float srow[NTOK];
  __shared__ unsigned hist[4][256];
  __shared__ unsigned l3hist[256];
  __shared__ float red[8];
  __shared__ unsigned sres[2];
  const int tid = threadIdx.x;
  const int wv = tid >> 6;
  const size_t base = (size_t)blockIdx.x * NTOK;

  for (int i = tid; i < 1024; i += 256) ((unsigned*)hist)[i] = 0;
  __syncthreads();
  float mx = -3.4e38f;
  for (int j = tid; j < NTOK; j += 256) {
    float v = sc[base + j];
    srow[j] = v;
    mx = fmaxf(mx, v);
    unsigned u = f2ord(v);
    atomicAdd(&hist[wv][u >> 24], 1u);
  }
#pragma unroll
  for (int off = 32; off; off >>= 1) mx = fmaxf(mx, __shfl_down(mx, off));
  if ((tid & 63) == 0) red[wv] = mx;
  __syncthreads();
  mx = fmaxf(fmaxf(red[0], red[1]), fmaxf(red[2], red[3]));
  l3hist[tid] = hist[0][tid] + hist[1][tid] + hist[2][tid] + hist[3][tid];
  __syncthreads();

  unsigned thr[2];
  const int kwant[2] = {KSEL1, KSEL2};
  for (int sel = 0; sel < 2; ++sel) {
    unsigned prefix = 0, pmask = 0;
    unsigned krem = (unsigned)kwant[sel];
    for (int lvl = 3; lvl >= 0; --lvl) {
      const int shift = lvl * 8;
      if (lvl < 3) {
        for (int i = tid; i < 1024; i += 256) ((unsigned*)hist)[i] = 0;
        __syncthreads();
        for (int j = tid; j < NTOK; j += 256) {
          unsigned u = f2ord(srow[j]);
          if ((u & pmask) == prefix) atomicAdd(&hist[wv][(u >> shift) & 255u], 1u);
        }
        __syncthreads();
      }
      // wave 0: suffix scan over 256 bins (4 per lane) + branch-point find
      if (tid < 64) {
        const int lane = tid;
        unsigned h0, h1, h2, h3;
        if (lvl == 3) {
          h0 = l3hist[lane * 4 + 0]; h1 = l3hist[lane * 4 + 1];
          h2 = l3hist[lane * 4 + 2]; h3 = l3hist[lane * 4 + 3];
        } else {
          int b0i = lane * 4;
          h0 = hist[0][b0i+0] + hist[1][b0i+0] + hist[2][b0i+0] + hist[3][b0i+0];
          h1 = hist[0][b0i+1] + hist[1][b0i+1] + hist[2][b0i+1] + hist[3][b0i+1];
          h2 = hist[0][b0i+2] + hist[1][b0i+2] + hist[2][b0i+2] + hist[3][b0i+2];
          h3 = hist[0][b0i+3] + hist[1][b0i+3] + hist[2][b0i+3] + hist[3][b0i+3];
        }
        unsigned s3 = h3, s2 = h2 + s3, s1 = h1 + s2, s0 = h0 + s1;
        unsigned acc = s0;
#pragma unroll
        for (int off = 1; off < 64; off <<= 1) {
          unsigned t = __shfl_down(acc, off);
          if (lane + off < 64) acc += t;
        }
        unsigned tail = __shfl_down(acc, 1);
        if (lane == 63) tail = 0;
        unsigned suf[4] = {tail + s0, tail + s1, tail + s2, tail + s3};
        unsigned nxt[4] = {tail + s1, tail + s2, tail + s3, tail};
#pragma unroll
        for (int i = 0; i < 4; ++i) {
          if (suf[i] >= krem && nxt[i] < krem) {
            sres[0] = (unsigned)(lane * 4 + i);
            sres[1] = krem - nxt[i];
          }
        }
      }
      __syncthreads();
      prefix |= sres[0] << shift;
      pmask |= 0xFFu << shift;
      krem = sres[1];
      __syncthreads();
    }
    thr[sel] = prefix;
  }
  const float t1 = ord2f(thr[0]), t2 = ord2f(thr[1]);
  float d1 = 0.f, d2 = 0.f;
  for (int j = tid; j < NTOK; j += 256) {
    float v = srow[j];
    float e = __expf(v - mx);
    if (v >= t1) d1 += e;
    if (v >= t2) d2 += e;
  }
#pragma unroll
  for (int off = 32; off; off >>= 1) { d1 += __shfl_down(d1, off); d2 += __shfl_down(d2, off); }
  if ((tid & 63) == 0) { red[wv] = d1; red[4 + wv] = d2; }
  __syncthreads();
  if (tid == 0) {
    d1 = red[0] + red[1] + red[2] + red[3];
    d2 = red[4] + red[5] + red[6] + red[7];
    float* st = stats + (size_t)blockIdx.x * 8;
    st[0] = mx;
    st[1] = t1;
    st[2] = t2;
    st[3] = w1p[0] / d1;
    st[4] = w2p[0] / d2;
  }
}

// ---------------------------------------------------------------------------
// Kernel F: out[b,n,h*32+d] += sum_{m in split} weight(s[n,m]) * v[m,d].
// 256-row x 32-col tile per block, TM=8 x TN=4 register blocking,
// split-m (blockIdx.y) with atomicAdd combine into zeroed oat.
#define PVR 256
#define PVM 32
#define PVS 9
__global__ __launch_bounds__(256) void pv_kernel(const float* __restrict__ sc,
                                                 const float* __restrict__ kvm,
                                                 const float* __restrict__ stats,
                                                 float* __restrict__ oat, int bh0) {
  __shared__ float Wt[PVM][PVR + 4];   // pitch 260: 16B-aligned rows, 2-way read alias
  __shared__ float Vs[PVM][HDIM + 4];  // pitch 36
  __shared__ float rst[PVR][5];
  const int rt = blockIdx.x;           // 0..8 row tile
  const int ms = blockIdx.y;           // 0..PVS-1 m split
  const int z  = blockIdx.z;           // local bh
  const int gbh = bh0 + z;
  const int b = gbh >> 3, h = gbh & 7;
  const int n0 = rt * PVR;
  const int tid = threadIdx.x;
  for (int i = tid; i < PVR * 5; i += 256) {
    int r = i / 5, f = i % 5;
    rst[r][f] = stats[((size_t)z * NTOK + n0 + r) * 8 + f];
  }
  __syncthreads();
  const int ty = tid >> 3;   // 0..31 row group
  const int tx = tid & 7;    // 0..7 col group
  float acc[8][4] = {};
  const int msteps = (NTOK / PVM) / PVS;   // 8
  for (int s = 0; s < msteps; ++s) {
    const int m0 = (ms * msteps + s) * PVM;
#pragma unroll
    for (int i = 0; i < 4; ++i) {         // stage V [32 m][32 d]
      int idx = tid + i * 256;
      int mm = idx >> 5, dd = idx & 31;
      Vs[mm][dd] = kvm[((size_t)(b * NTOK + m0 + mm)) * (2 * CC) + CC + h * HDIM + dd];
    }
#pragma unroll
    for (int i = 0; i < 32; ++i) {        // stage weights [256 r][32 m]
      int idx = tid + i * 256;
      int r = idx >> 5, mm = idx & 31;
      float sv = sc[((size_t)z * NTOK + n0 + r) * NTOK + m0 + mm];
      float e = __expf(sv - rst[r][0]);
      float w = 0.f;
      if (sv >= rst[r][1]) w += rst[r][3];
      if (sv >= rst[r][2]) w += rst[r][4];
      Wt[mm][r] = e * w;
    }
    __syncthreads();
#pragma unroll
    for (int mm = 0; mm < PVM; ++mm) {
      float a0[8], b0[4];
#pragma unroll
      for (int i = 0; i < 8; ++i) a0[i] = Wt[mm][ty * 8 + i];
#pragma unroll
      for (int j = 0; j < 4; ++j) b0[j] = Vs[mm][tx * 4 + j];
#pragma unroll
      for (int i = 0; i < 8; ++i)
#pragma unroll
        for (int j = 0; j < 4; ++j) acc[i][j] += a0[i] * b0[j];
    }
    __syncthreads();
  }
#pragma unroll
  for (int i = 0; i < 8; ++i) {
    int n = n0 + ty * 8 + i;
    float* dst = &oat[((size_t)(b * NTOK + n)) * CC + h * HDIM + tx * 4];
#pragma unroll
    for (int j = 0; j < 4; ++j) atomicAdd(&dst[j], acc[i][j]);
  }
}

// ---------------------------------------------------------------------------
extern "C" void kernel_launch(void* const* d_in, const int* in_sizes, int n_in,
                              void* d_out, int out_size, void* d_ws, size_t ws_size,
                              hipStream_t stream) {
  const float* x     = (const float*)d_in[0];
  const float* y     = (const float*)d_in[1];
  const float* Wq    = (const float*)d_in[2];
  const float* Wkv   = (const float*)d_in[3];
  const float* Wproj = (const float*)d_in[4];
  const float* bproj = (const float*)d_in[5];
  const float* gamma = (const float*)d_in[6];
  const float* beta  = (const float*)d_in[7];
  const float* aw1   = (const float*)d_in[8];
  const float* aw2   = (const float*)d_in[9];

  float* ws = (float*)d_ws;
  const size_t SZ_PLANE = (size_t)BB * CC * NTOK;          // 1,179,648
  float* yp    = ws;                                       // [B,C,N]
  float* yt    = yp + SZ_PLANE;                            // [B,N,C]
  float* qb    = yt + SZ_PLANE;                            // [B,N,C]
  float* kvb   = qb + SZ_PLANE;                            // [B,N,2C]
  float* stats = kvb + 2 * SZ_PLANE;                       // [16*2304, 8]
  float* oat   = stats + (size_t)NBH * NTOK * 8;           // [B,N,C]
  float* sc    = oat + SZ_PLANE;                           // [CH, N, N]

  // choose bh-chunk size from available workspace; cap at 8 so the score
  // slice (170 MB) stays L3-resident (256 MB).
  const long long fixed_f = (long long)(sc - ws);
  const long long avail_f = (long long)(ws_size / 4) - fixed_f;
  int CH = 8;
  while (CH > 1 && (long long)CH * NTOK * NTOK > avail_f) CH >>= 1;

  pool_kernel<<<dim3(BB * CC), 256, 0, stream>>>(y, yp);
  ln_kernel<<<dim3(BB * NTOK), 256, 0, stream>>>(yp, gamma, beta, yt);
  gemm64_kernel<1><<<dim3(BB * NTOK / 64, CC / 64), 256, 0, stream>>>(
      x, Wq, nullptr, qb, CC, CC, 0);
  gemm64_kernel<0><<<dim3(BB * NTOK / 64, 2 * CC / 64), 256, 0, stream>>>(
      yt, Wkv, nullptr, kvb, CC, 2 * CC, 0);

  hipMemsetAsync(oat, 0, SZ_PLANE * sizeof(float), stream);

  const int nch = NBH / CH;
  for (int ch = 0; ch < nch; ++ch) {
    int bh0 = ch * CH;
    score_kernel<<<dim3(NTOK / 64, NTOK / 64, CH), 256, 0, stream>>>(qb, kvb, sc, bh0);
    select_kernel<<<dim3(CH * NTOK), 256, 0, stream>>>(sc, stats, aw1, aw2);
    pv_kernel<<<dim3(NTOK / PVR, PVS, CH), 256, 0, stream>>>(sc, kvb, stats, oat, bh0);
  }

  gemm64_kernel<0><<<dim3(BB * NTOK / 64, CC / 64), 256, 0, stream>>>(
      oat, Wproj, bproj, (float*)d_out, CC, CC, 1);
}

// Round 3
// 616.880 us; speedup vs baseline: 2.1591x; 2.1106x over previous
//
#include <hip/hip_runtime.h>

// Problem constants
#define BB     2
#define CC     256
#define HH     48
#define WW     48
#define NTOK   2304          // H*W
#define NHEADS 8
#define HDIM   32
#define NBH    16            // BB*NHEADS
#define SCALE_QK 0.17677669529663687f  // 1/sqrt(32)
#define KSEL1  1152          // N1 // 2
#define KSEL2  768           // N1 // 3

typedef _Float16 f16x8 __attribute__((ext_vector_type(8)));
typedef float f32x4 __attribute__((ext_vector_type(4)));

__device__ __forceinline__ unsigned f2ord(float f) {
  unsigned u = __float_as_uint(f);
  return (u & 0x80000000u) ? ~u : (u | 0x80000000u);
}
__device__ __forceinline__ float ord2f(unsigned u) {
  unsigned b = (u & 0x80000000u) ? (u & 0x7fffffffu) : ~u;
  return __uint_as_float(b);
}

// ---------------------------------------------------------------------------
// Kernel A: multi-scale avg pool (3,5,7 box filters, count_include_pad) via
// per-plane integral image. One block per (b,c) plane.
__global__ __launch_bounds__(256) void pool_kernel(const float* __restrict__ y,
                                                   float* __restrict__ yp) {
  __shared__ float sp[HH * WW];
  __shared__ float I[49 * 49];
  const int bc = blockIdx.x;
  const float* src = y + (size_t)bc * (HH * WW);
  for (int i = threadIdx.x; i < HH * WW; i += 256) sp[i] = src[i];
  __syncthreads();
  if (threadIdx.x < 48) {            // row prefix sums
    int r = threadIdx.x;
    float acc = 0.f;
    I[(r + 1) * 49 + 0] = 0.f;
    for (int j = 0; j < 48; ++j) { acc += sp[r * 48 + j]; I[(r + 1) * 49 + j + 1] = acc; }
  } else if (threadIdx.x < 97) {     // zero top row
    int j = threadIdx.x - 48;
    I[j] = 0.f;
  }
  __syncthreads();
  if (threadIdx.x < 48) {            // column prefix sums
    int j = threadIdx.x + 1;
    float acc = 0.f;
    for (int i = 1; i <= 48; ++i) { acc += I[i * 49 + j]; I[i * 49 + j] = acc; }
  }
  __syncthreads();
  for (int n = threadIdx.x; n < HH * WW; n += 256) {
    int i = n / 48, j = n % 48;
    float r = 0.f;
#pragma unroll
    for (int kk = 0; kk < 3; ++kk) {
      int p = 1 + kk;                 // kernel 3,5,7 -> pad 1,2,3
      int i0 = i - p; if (i0 < 0) i0 = 0;
      int j0 = j - p; if (j0 < 0) j0 = 0;
      int i1 = i + p + 1; if (i1 > 48) i1 = 48;
      int j1 = j + p + 1; if (j1 > 48) j1 = 48;
      float s = I[i1 * 49 + j1] - I[i0 * 49 + j1] - I[i1 * 49 + j0] + I[i0 * 49 + j0];
      int k = 2 * p + 1;
      r += s / (float)(k * k);
    }
    yp[(size_t)bc * (HH * WW) + n] = r;
  }
}

// ---------------------------------------------------------------------------
// Kernel B: LayerNorm over C, transpose to [B, N, C]. One block per (b,n).
__global__ __launch_bounds__(256) void ln_kernel(const float* __restrict__ yp,
                                                 const float* __restrict__ gamma,
                                                 const float* __restrict__ beta,
                                                 float* __restrict__ yt) {
  const int bn = blockIdx.x;
  const int b = bn / NTOK, n = bn % NTOK;
  const int c = threadIdx.x;
  float v = yp[((size_t)(b * CC + c)) * NTOK + n];
  float s = v, s2 = v * v;
#pragma unroll
  for (int off = 32; off; off >>= 1) { s += __shfl_down(s, off); s2 += __shfl_down(s2, off); }
  __shared__ float ws[8];
  int wid = threadIdx.x >> 6, lane = threadIdx.x & 63;
  if (lane == 0) { ws[wid] = s; ws[4 + wid] = s2; }
  __syncthreads();
  s = ws[0] + ws[1] + ws[2] + ws[3];
  s2 = ws[4] + ws[5] + ws[6] + ws[7];
  float mean = s * (1.f / CC);
  float var = s2 * (1.f / CC) - mean * mean;
  float rstd = rsqrtf(var + 1e-5f);
  yt[(size_t)bn * CC + c] = (v - mean) * rstd * gamma[c] + beta[c];
}

// ---------------------------------------------------------------------------
// Generic 64x64-tile fp32 GEMM: C = A[M,K] @ B[K,Nc] (+bias).
// ATRANS=1: A is x in [B,C,N] layout, A[row,k] = x[b,k,n].
// trans_out=1: write Cm[b, col, n] (for the final projection into d_out).
template <int ATRANS>
__global__ __launch_bounds__(256) void gemm64_kernel(const float* __restrict__ A,
                                                     const float* __restrict__ Bm,
                                                     const float* __restrict__ bias,
                                                     float* __restrict__ Cm,
                                                     int K, int Nc, int trans_out) {
  __shared__ float smem[64 * 65];      // reused: As[16][68] + Bs[16][68], then Ts[64][65]
  float* As = smem;
  float* Bs = smem + 16 * 68;
  const int row0 = blockIdx.x * 64;
  const int col0 = blockIdx.y * 64;
  const int tid = threadIdx.x;
  const int ty = tid >> 4, tx = tid & 15;
  const int b = row0 / NTOK, n0 = row0 % NTOK;
  float acc[4][4] = {};
  for (int k0 = 0; k0 < K; k0 += 16) {
    if (ATRANS) {
#pragma unroll
      for (int it = 0; it < 4; ++it) {
        int idx = tid + it * 256;
        int kk = idx >> 6, r = idx & 63;
        As[kk * 68 + r] = A[((size_t)(b * CC + k0 + kk)) * NTOK + n0 + r];
      }
    } else {
#pragma unroll
      for (int it = 0; it < 4; ++it) {
        int idx = tid + it * 256;
        int kk = idx & 15, r = idx >> 4;
        As[kk * 68 + r] = A[(size_t)(row0 + r) * K + k0 + kk];
      }
    }
#pragma unroll
    for (int it = 0; it < 4; ++it) {
      int idx = tid + it * 256;
      int kk = idx >> 6, c = idx & 63;
      Bs[kk * 68 + c] = Bm[(size_t)(k0 + kk) * Nc + col0 + c];
    }
    __syncthreads();
#pragma unroll
    for (int kk = 0; kk < 16; ++kk) {
      float a0[4], b0[4];
#pragma unroll
      for (int i = 0; i < 4; ++i) a0[i] = As[kk * 68 + ty * 4 + i];
#pragma unroll
      for (int j = 0; j < 4; ++j) b0[j] = Bs[kk * 68 + tx * 4 + j];
#pragma unroll
      for (int i = 0; i < 4; ++i)
#pragma unroll
        for (int j = 0; j < 4; ++j) acc[i][j] += a0[i] * b0[j];
    }
    __syncthreads();
  }
  if (!trans_out) {
#pragma unroll
    for (int i = 0; i < 4; ++i)
#pragma unroll
      for (int j = 0; j < 4; ++j) {
        int row = row0 + ty * 4 + i, col = col0 + tx * 4 + j;
        float v = acc[i][j] + (bias ? bias[col] : 0.f);
        Cm[(size_t)row * Nc + col] = v;
      }
  } else {
    float* Ts = smem;
    __syncthreads();
#pragma unroll
    for (int i = 0; i < 4; ++i)
#pragma unroll
      for (int j = 0; j < 4; ++j) Ts[(ty * 4 + i) * 65 + tx * 4 + j] = acc[i][j];
    __syncthreads();
#pragma unroll
    for (int it = 0; it < 16; ++it) {
      int idx = tid + it * 256;
      int c = idx >> 6, r = idx & 63;
      float v = Ts[r * 65 + c] + (bias ? bias[col0 + c] : 0.f);
      Cm[((size_t)(b * Nc + col0 + c)) * NTOK + n0 + r] = v;
    }
  }
}

// ---------------------------------------------------------------------------
// Kernel D: scores = scale * q @ k^T, per (b,h) slice. Chunked over bh.
__global__ __launch_bounds__(256) void score_kernel(const float* __restrict__ qm,
                                                    const float* __restrict__ kvm,
                                                    float* __restrict__ sc, int bh0) {
  __shared__ float Qs[32 * 68];
  __shared__ float Ks[32 * 68];
  const int n0 = blockIdx.x * 64, m0 = blockIdx.y * 64;
  const int z = blockIdx.z;
  const int gbh = bh0 + z;
  const int b = gbh >> 3, h = gbh & 7;
  const int tid = threadIdx.x;
  {
    int kk = tid & 31, rb = tid >> 5;
#pragma unroll
    for (int i = 0; i < 8; ++i) {
      int r = rb * 8 + i;
      Qs[kk * 68 + r] = qm[((size_t)(b * NTOK + n0 + r)) * CC + h * HDIM + kk];
      Ks[kk * 68 + r] = kvm[((size_t)(b * NTOK + m0 + r)) * (2 * CC) + h * HDIM + kk];
    }
  }
  __syncthreads();
  const int ty = tid >> 4, tx = tid & 15;
  float acc[4][4] = {};
#pragma unroll
  for (int kk = 0; kk < 32; ++kk) {
    float a0[4], b0[4];
#pragma unroll
    for (int i = 0; i < 4; ++i) a0[i] = Qs[kk * 68 + ty * 4 + i];
#pragma unroll
    for (int j = 0; j < 4; ++j) b0[j] = Ks[kk * 68 + tx * 4 + j];
#pragma unroll
    for (int i = 0; i < 4; ++i)
#pragma unroll
      for (int j = 0; j < 4; ++j) acc[i][j] += a0[i] * b0[j];
  }
#pragma unroll
  for (int i = 0; i < 4; ++i) {
    size_t rowbase = ((size_t)z * NTOK + n0 + ty * 4 + i) * NTOK + m0;
#pragma unroll
    for (int j = 0; j < 4; ++j) sc[rowbase + tx * 4 + j] = acc[i][j] * SCALE_QK;
  }
}

// ---------------------------------------------------------------------------
// Kernel E: per-row max, radix-select thresholds for k=1152 and k=768,
// partial exp-sums D1, D2. One block (256 threads) per score row.
__global__ __launch_bounds__(256) void select_kernel(const float* __restrict__ sc,
                                                     float* __restrict__ stats,
                                                     const float* __restrict__ w1p,
                                                     const float* __restrict__ w2p) {
  __shared__ float srow[NTOK];
  __shared__ unsigned hist[4][256];
  __shared__ unsigned l3hist[256];
  __shared__ float red[8];
  __shared__ unsigned sres[2];
  const int tid = threadIdx.x;
  const int wv = tid >> 6;
  const size_t base = (size_t)blockIdx.x * NTOK;

  for (int i = tid; i < 1024; i += 256) ((unsigned*)hist)[i] = 0;
  __syncthreads();
  float mx = -3.4e38f;
  for (int j = tid; j < NTOK; j += 256) {
    float v = sc[base + j];
    srow[j] = v;
    mx = fmaxf(mx, v);
    unsigned u = f2ord(v);
    atomicAdd(&hist[wv][u >> 24], 1u);
  }
#pragma unroll
  for (int off = 32; off; off >>= 1) mx = fmaxf(mx, __shfl_down(mx, off));
  if ((tid & 63) == 0) red[wv] = mx;
  __syncthreads();
  mx = fmaxf(fmaxf(red[0], red[1]), fmaxf(red[2], red[3]));
  l3hist[tid] = hist[0][tid] + hist[1][tid] + hist[2][tid] + hist[3][tid];
  __syncthreads();

  unsigned thr[2];
  const int kwant[2] = {KSEL1, KSEL2};
  for (int sel = 0; sel < 2; ++sel) {
    unsigned prefix = 0, pmask = 0;
    unsigned krem = (unsigned)kwant[sel];
    for (int lvl = 3; lvl >= 0; --lvl) {
      const int shift = lvl * 8;
      if (lvl < 3) {
        for (int i = tid; i < 1024; i += 256) ((unsigned*)hist)[i] = 0;
        __syncthreads();
        for (int j = tid; j < NTOK; j += 256) {
          unsigned u = f2ord(srow[j]);
          if ((u & pmask) == prefix) atomicAdd(&hist[wv][(u >> shift) & 255u], 1u);
        }
        __syncthreads();
      }
      // wave 0: suffix scan over 256 bins (4 per lane) + branch-point find
      if (tid < 64) {
        const int lane = tid;
        unsigned h0, h1, h2, h3;
        if (lvl == 3) {
          h0 = l3hist[lane * 4 + 0]; h1 = l3hist[lane * 4 + 1];
          h2 = l3hist[lane * 4 + 2]; h3 = l3hist[lane * 4 + 3];
        } else {
          int b0i = lane * 4;
          h0 = hist[0][b0i+0] + hist[1][b0i+0] + hist[2][b0i+0] + hist[3][b0i+0];
          h1 = hist[0][b0i+1] + hist[1][b0i+1] + hist[2][b0i+1] + hist[3][b0i+1];
          h2 = hist[0][b0i+2] + hist[1][b0i+2] + hist[2][b0i+2] + hist[3][b0i+2];
          h3 = hist[0][b0i+3] + hist[1][b0i+3] + hist[2][b0i+3] + hist[3][b0i+3];
        }
        unsigned s3 = h3, s2 = h2 + s3, s1 = h1 + s2, s0 = h0 + s1;
        unsigned acc = s0;
#pragma unroll
        for (int off = 1; off < 64; off <<= 1) {
          unsigned t = __shfl_down(acc, off);
          if (lane + off < 64) acc += t;
        }
        unsigned tail = __shfl_down(acc, 1);
        if (lane == 63) tail = 0;
        unsigned suf[4] = {tail + s0, tail + s1, tail + s2, tail + s3};
        unsigned nxt[4] = {tail + s1, tail + s2, tail + s3, tail};
#pragma unroll
        for (int i = 0; i < 4; ++i) {
          if (suf[i] >= krem && nxt[i] < krem) {
            sres[0] = (unsigned)(lane * 4 + i);
            sres[1] = krem - nxt[i];
          }
        }
      }
      __syncthreads();
      prefix |= sres[0] << shift;
      pmask |= 0xFFu << shift;
      krem = sres[1];
      __syncthreads();
    }
    thr[sel] = prefix;
  }
  const float t1 = ord2f(thr[0]), t2 = ord2f(thr[1]);
  float d1 = 0.f, d2 = 0.f;
  for (int j = tid; j < NTOK; j += 256) {
    float v = srow[j];
    float e = __expf(v - mx);
    if (v >= t1) d1 += e;
    if (v >= t2) d2 += e;
  }
#pragma unroll
  for (int off = 32; off; off >>= 1) { d1 += __shfl_down(d1, off); d2 += __shfl_down(d2, off); }
  if ((tid & 63) == 0) { red[wv] = d1; red[4 + wv] = d2; }
  __syncthreads();
  if (tid == 0) {
    d1 = red[0] + red[1] + red[2] + red[3];
    d2 = red[4] + red[5] + red[6] + red[7];
    float* st = stats + (size_t)blockIdx.x * 8;
    st[0] = mx;
    st[1] = t1;
    st[2] = t2;
    st[3] = w1p[0] / d1;
    st[4] = w2p[0] / d2;
  }
}

// ---------------------------------------------------------------------------
// Kernel V: vtb[bh][d][m] = (f16) kv_v[b][m][h*32+d]  (transposed f16 V table)
__global__ __launch_bounds__(256) void vcast_kernel(const float* __restrict__ kvm,
                                                    _Float16* __restrict__ vtb) {
  int idx = blockIdx.x * 256 + threadIdx.x;   // over 16*32*2304
  int m = idx % NTOK;
  int t = idx / NTOK;          // bh*32 + d
  int d = t & 31;
  int bh = t >> 5;
  int b = bh >> 3, h = bh & 7;
  vtb[idx] = (_Float16)kvm[((size_t)(b * NTOK + m)) * (2 * CC) + CC + h * HDIM + d];
}

// ---------------------------------------------------------------------------
// Kernel F: PV via MFMA, zero LDS. Wave w of each block owns a 16(n) x 32(d)
// output tile. Per 32-m step: lane computes its 8 A-frag weights straight
// from the f32 score row (A layout: row=lane&15, k=(lane>>4)*8+i), converts
// to f16, MFMAs against the pre-transposed f16 V table. m-split over
// blockIdx.y, combined with atomicAdd into zeroed oat.
#define MSPLIT 4
__global__ __launch_bounds__(256) void pv_mfma_kernel(const float* __restrict__ sc,
                                                      const _Float16* __restrict__ vtb,
                                                      const float* __restrict__ stats,
                                                      float* __restrict__ oat, int bh0) {
  const int w = threadIdx.x >> 6;
  const int l = threadIdx.x & 63;
  const int z = blockIdx.z;
  const int gbh = bh0 + z;
  const int b = gbh >> 3, h = gbh & 7;
  const int n0 = blockIdx.x * 64 + w * 16;
  const int row = l & 15;            // A row / C col (d within half)
  const int kg = l >> 4;             // k-group
  const int n = n0 + row;
  const float* st = stats + ((size_t)z * NTOK + n) * 8;
  const float mx = st[0], t1 = st[1], t2 = st[2], w1d = st[3], w2d = st[4];
  const float* srow = sc + ((size_t)z * NTOK + n) * NTOK;
  const _Float16* v0 = vtb + ((size_t)gbh * HDIM + row) * NTOK;
  const _Float16* v1 = v0 + 16 * NTOK;
  f32x4 acc0 = {0.f, 0.f, 0.f, 0.f};
  f32x4 acc1 = {0.f, 0.f, 0.f, 0.f};
  const int msteps = (NTOK / 32) / MSPLIT;   // 18
  int m0 = blockIdx.y * msteps * 32 + kg * 8;
#pragma unroll 2
  for (int s = 0; s < msteps; ++s, m0 += 32) {
    f32x4 sa = *(const f32x4*)(srow + m0);
    f32x4 sb = *(const f32x4*)(srow + m0 + 4);
    f16x8 afr;
#pragma unroll
    for (int i = 0; i < 8; ++i) {
      float sv = (i < 4) ? sa[i] : sb[i - 4];
      float e = __expf(sv - mx);
      float wgt = (sv >= t1 ? w1d : 0.f) + (sv >= t2 ? w2d : 0.f);
      afr[i] = (_Float16)(e * wgt);
    }
    f16x8 bfr0 = *(const f16x8*)(v0 + m0);
    f16x8 bfr1 = *(const f16x8*)(v1 + m0);
    acc0 = __builtin_amdgcn_mfma_f32_16x16x32_f16(afr, bfr0, acc0, 0, 0, 0);
    acc1 = __builtin_amdgcn_mfma_f32_16x16x32_f16(afr, bfr1, acc1, 0, 0, 0);
  }
  // C/D layout: col = lane&15 (=row var), row = (lane>>4)*4 + reg
#pragma unroll
  for (int r = 0; r < 4; ++r) {
    int nn = n0 + kg * 4 + r;
    float* dst = &oat[((size_t)(b * NTOK + nn)) * CC + h * HDIM];
    atomicAdd(&dst[row], acc0[r]);
    atomicAdd(&dst[16 + row], acc1[r]);
  }
}

// ---------------------------------------------------------------------------
extern "C" void kernel_launch(void* const* d_in, const int* in_sizes, int n_in,
                              void* d_out, int out_size, void* d_ws, size_t ws_size,
                              hipStream_t stream) {
  const float* x     = (const float*)d_in[0];
  const float* y     = (const float*)d_in[1];
  const float* Wq    = (const float*)d_in[2];
  const float* Wkv   = (const float*)d_in[3];
  const float* Wproj = (const float*)d_in[4];
  const float* bproj = (const float*)d_in[5];
  const float* gamma = (const float*)d_in[6];
  const float* beta  = (const float*)d_in[7];
  const float* aw1   = (const float*)d_in[8];
  const float* aw2   = (const float*)d_in[9];

  float* ws = (float*)d_ws;
  const size_t SZ_PLANE = (size_t)BB * CC * NTOK;          // 1,179,648
  float* yp    = ws;                                       // [B,C,N]
  float* yt    = yp + SZ_PLANE;                            // [B,N,C]
  float* qb    = yt + SZ_PLANE;                            // [B,N,C]
  float* kvb   = qb + SZ_PLANE;                            // [B,N,2C]
  float* stats = kvb + 2 * SZ_PLANE;                       // [16*2304, 8]
  float* oat   = stats + (size_t)NBH * NTOK * 8;           // [B,N,C]
  _Float16* vtb = (_Float16*)(oat + SZ_PLANE);             // [16][32][2304] f16
  float* sc    = oat + SZ_PLANE + SZ_PLANE / 2;            // [CH, N, N]

  // choose bh-chunk size from available workspace; cap at 8 so the score
  // slice (170 MB) stays L3-resident (256 MB).
  const long long fixed_f = (long long)(sc - ws);
  const long long avail_f = (long long)(ws_size / 4) - fixed_f;
  int CH = 8;
  while (CH > 1 && (long long)CH * NTOK * NTOK > avail_f) CH >>= 1;

  pool_kernel<<<dim3(BB * CC), 256, 0, stream>>>(y, yp);
  ln_kernel<<<dim3(BB * NTOK), 256, 0, stream>>>(yp, gamma, beta, yt);
  gemm64_kernel<1><<<dim3(BB * NTOK / 64, CC / 64), 256, 0, stream>>>(
      x, Wq, nullptr, qb, CC, CC, 0);
  gemm64_kernel<0><<<dim3(BB * NTOK / 64, 2 * CC / 64), 256, 0, stream>>>(
      yt, Wkv, nullptr, kvb, CC, 2 * CC, 0);
  vcast_kernel<<<dim3((NBH * HDIM * NTOK) / 256), 256, 0, stream>>>(kvb, vtb);

  hipMemsetAsync(oat, 0, SZ_PLANE * sizeof(float), stream);

  const int nch = NBH / CH;
  for (int ch = 0; ch < nch; ++ch) {
    int bh0 = ch * CH;
    score_kernel<<<dim3(NTOK / 64, NTOK / 64, CH), 256, 0, stream>>>(qb, kvb, sc, bh0);
    select_kernel<<<dim3(CH * NTOK), 256, 0, stream>>>(sc, stats, aw1, aw2);
    pv_mfma_kernel<<<dim3(NTOK / 64, MSPLIT, CH), 256, 0, stream>>>(sc, vtb, stats, oat, bh0);
  }

  gemm64_kernel<0><<<dim3(BB * NTOK / 64, CC / 64), 256, 0, stream>>>(
      oat, Wproj, bproj, (float*)d_out, CC, CC, 1);
}